// Round 6
// baseline (136.763 us; speedup 1.0000x reference)
//
#include <hip/hip_runtime.h>
#include <hip/hip_bf16.h>
#include <math.h>

#define NQ 50000
#define NS 50000
#define KK 32
#define CF 64      // feat channels
#define CW 67      // conv input channels (3 + 64)
#define CO 64      // output channels
#define WAVES 4
#define GRIDM 1280            // 5 blocks/CU
#define GS2 (GRIDM * WAVES)   // 5120 queries per grid-stride step

typedef __attribute__((ext_vector_type(8))) short bf16x8;
typedef __attribute__((ext_vector_type(16))) float f32x16;

__device__ inline short f2b(float x) {
    union { __hip_bfloat16 b; short s; } u;
    u.b = __float2bfloat16(x);   // RNE
    return u.s;
}

__device__ inline bf16x8 pack2(const float4 a, const float4 b) {
    bf16x8 r;
    r[0] = f2b(a.x); r[1] = f2b(a.y); r[2] = f2b(a.z); r[3] = f2b(a.w);
    r[4] = f2b(b.x); r[5] = f2b(b.y); r[6] = f2b(b.z); r[7] = f2b(b.w);
    return r;
}

__device__ inline bf16x8 zero8() {
    bf16x8 r;
#pragma unroll
    for (int j = 0; j < 8; ++j) r[j] = 0;
    return r;
}

// feat f32 [NS][64] -> bf16 table [NS+1][64] (row NS = zeros).
__global__ __launch_bounds__(256) void gc_tobf16(const float* __restrict__ feat,
                                                 bf16x8* __restrict__ fbf)
{
    const int i = blockIdx.x * 256 + threadIdx.x;     // short8 index
    if (i >= (NS + 1) * CF / 8) return;
    bf16x8 r;
    if (i < NS * CF / 8) {
        const float4* fp = (const float4*)feat + (size_t)i * 2;
        r = pack2(fp[0], fp[1]);
    } else {
        r = zero8();
    }
    fbf[i] = r;
}

// One wave = one query per iteration. M=32 neighbors, N=64 (2 tiles of 32),
// K=80 (k0..63 = feat channels via bf16 table, k64..66 = rel coords).
// Software-pipelined 1 iteration ahead; indices 2 ahead.
template <bool TAB, bool MIN>
__global__ __launch_bounds__(256, 5) void gc_mfma(
    const float* __restrict__ qp,
    const float* __restrict__ sp,
    const float* __restrict__ feat,
    const bf16x8* __restrict__ fbf,   // [NS+1][8] short8 rows
    const float* __restrict__ w,      // [64][67]
    const int*   __restrict__ inds,
    float* __restrict__ zmax,         // d_out [NQ][64]
    float* __restrict__ zmin,         // ws (optional)
    float* __restrict__ partials)     // [GRIDM][128]
{
    __shared__ float red[WAVES][128];

    const int tid  = threadIdx.x;
    const int lane = tid & 63;
    const int wv   = tid >> 6;
    const int col  = lane & 31;
    const int half = lane >> 5;

    // ---- B fragments (weights), register-resident, built once ----
    bf16x8 bfrag[5][2];
#pragma unroll
    for (int c = 0; c < 5; ++c) {
#pragma unroll
        for (int t = 0; t < 2; ++t) {
            const int o = t * 32 + col;
            bf16x8 r;
#pragma unroll
            for (int j = 0; j < 8; ++j) {
                const int k = c * 16 + half * 8 + j;
                float v = 0.f;
                if (k < 64)      v = w[o * CW + 3 + k];
                else if (k < 67) v = w[o * CW + (k - 64)];
                r[j] = f2b(v);
            }
            bfrag[c][t] = r;
        }
    }

    float csum0 = 0.f, csum1 = 0.f, csq0 = 0.f, csq1 = 0.f;

    // ---- pipeline prologue ----
    int q = blockIdx.x * WAVES + wv;          // < GS2 <= NQ
    int ii = inds[q * KK + col];
    bool vc = (ii < NS);
    bf16x8 A0, A1, A2, A3;
    float sx, sy, sz, qx, qy, qz;
    if (TAB) {
        const bf16x8* frow = fbf + (size_t)ii * 8;   // row NS is zeros
        A0 = frow[half]; A1 = frow[2 + half]; A2 = frow[4 + half]; A3 = frow[6 + half];
    } else {
        const int iic = vc ? ii : 0;
        const float4* fp = (const float4*)(feat + (size_t)iic * CF);
        A0 = pack2(fp[half * 2], fp[half * 2 + 1]);
        A1 = pack2(fp[4 + half * 2], fp[4 + half * 2 + 1]);
        A2 = pack2(fp[8 + half * 2], fp[8 + half * 2 + 1]);
        A3 = pack2(fp[12 + half * 2], fp[12 + half * 2 + 1]);
        if (!vc) { A0 = zero8(); A1 = zero8(); A2 = zero8(); A3 = zero8(); }
    }
    {
        const int iis = vc ? ii : 0;
        sx = sp[iis * 3 + 0]; sy = sp[iis * 3 + 1]; sz = sp[iis * 3 + 2];
        qx = qp[q * 3 + 0];   qy = qp[q * 3 + 1];   qz = qp[q * 3 + 2];
    }
    int qn  = q + GS2;
    int in2 = (qn < NQ) ? inds[qn * KK + col] : 0;

    while (true) {
        // ---- coord fragment (k=64..66) for current query ----
        bf16x8 a4 = zero8();
        if (half == 0) {
            a4[0] = f2b(vc ? sx - qx : 0.f);
            a4[1] = f2b(vc ? sy - qy : 0.f);
            a4[2] = f2b(vc ? sz - qz : 0.f);
        }

        // ---- issue next query's gather (covered by MFMA + epilogue) ----
        const bool have_next = (qn < NQ);   // wave-uniform
        bf16x8 N0, N1, N2, N3;
        float nsx = 0.f, nsy = 0.f, nsz = 0.f, nqx = 0.f, nqy = 0.f, nqz = 0.f;
        bool vn = false;
        int  in3 = 0;
        if (have_next) {
            vn = (in2 < NS);
            if (TAB) {
                const bf16x8* frow = fbf + (size_t)in2 * 8;
                N0 = frow[half]; N1 = frow[2 + half]; N2 = frow[4 + half]; N3 = frow[6 + half];
            } else {
                const int iic = vn ? in2 : 0;
                const float4* fp = (const float4*)(feat + (size_t)iic * CF);
                N0 = pack2(fp[half * 2], fp[half * 2 + 1]);
                N1 = pack2(fp[4 + half * 2], fp[4 + half * 2 + 1]);
                N2 = pack2(fp[8 + half * 2], fp[8 + half * 2 + 1]);
                N3 = pack2(fp[12 + half * 2], fp[12 + half * 2 + 1]);
                if (!vn) { N0 = zero8(); N1 = zero8(); N2 = zero8(); N3 = zero8(); }
            }
            const int iis = vn ? in2 : 0;
            nsx = sp[iis * 3 + 0]; nsy = sp[iis * 3 + 1]; nsz = sp[iis * 3 + 2];
            nqx = qp[qn * 3 + 0];  nqy = qp[qn * 3 + 1];  nqz = qp[qn * 3 + 2];
            const int qn2 = qn + GS2;
            if (qn2 < NQ) in3 = inds[qn2 * KK + col];
        }

        // ---- MFMA: C[32 rows=neighbors][64 cols=channels] ----
        f32x16 acc0, acc1;
#pragma unroll
        for (int r = 0; r < 16; ++r) { acc0[r] = 0.f; acc1[r] = 0.f; }
        acc0 = __builtin_amdgcn_mfma_f32_32x32x16_bf16(A0, bfrag[0][0], acc0, 0, 0, 0);
        acc1 = __builtin_amdgcn_mfma_f32_32x32x16_bf16(A0, bfrag[0][1], acc1, 0, 0, 0);
        acc0 = __builtin_amdgcn_mfma_f32_32x32x16_bf16(A1, bfrag[1][0], acc0, 0, 0, 0);
        acc1 = __builtin_amdgcn_mfma_f32_32x32x16_bf16(A1, bfrag[1][1], acc1, 0, 0, 0);
        acc0 = __builtin_amdgcn_mfma_f32_32x32x16_bf16(A2, bfrag[2][0], acc0, 0, 0, 0);
        acc1 = __builtin_amdgcn_mfma_f32_32x32x16_bf16(A2, bfrag[2][1], acc1, 0, 0, 0);
        acc0 = __builtin_amdgcn_mfma_f32_32x32x16_bf16(A3, bfrag[3][0], acc0, 0, 0, 0);
        acc1 = __builtin_amdgcn_mfma_f32_32x32x16_bf16(A3, bfrag[3][1], acc1, 0, 0, 0);
        acc0 = __builtin_amdgcn_mfma_f32_32x32x16_bf16(a4, bfrag[4][0], acc0, 0, 0, 0);
        acc1 = __builtin_amdgcn_mfma_f32_32x32x16_bf16(a4, bfrag[4][1], acc1, 0, 0, 0);

        // ---- epilogue: per-col max over 32 rows + sum/sumsq ----
        float m0 = acc0[0], m1 = acc1[0];
        float n0 = acc0[0], n1 = acc1[0];
        float s0 = 0.f, s1 = 0.f, q0 = 0.f, q1 = 0.f;
#pragma unroll
        for (int r = 0; r < 16; ++r) {
            const float z0 = acc0[r], z1 = acc1[r];
            m0 = fmaxf(m0, z0); m1 = fmaxf(m1, z1);
            if (MIN) { n0 = fminf(n0, z0); n1 = fminf(n1, z1); }
            s0 += z0; s1 += z1;
            q0 = fmaf(z0, z0, q0); q1 = fmaf(z1, z1, q1);
        }
        csum0 += s0; csum1 += s1; csq0 += q0; csq1 += q1;

        m0 = fmaxf(m0, __shfl_xor(m0, 32));
        m1 = fmaxf(m1, __shfl_xor(m1, 32));
        zmax[q * CO + half * 32 + col] = half ? m1 : m0;
        if (MIN) {
            n0 = fminf(n0, __shfl_xor(n0, 32));
            n1 = fminf(n1, __shfl_xor(n1, 32));
            zmin[q * CO + half * 32 + col] = half ? n1 : n0;
        }

        if (!have_next) break;
        q = qn; qn += GS2;
        ii = in2; in2 = in3; vc = vn;
        A0 = N0; A1 = N1; A2 = N2; A3 = N3;
        sx = nsx; sy = nsy; sz = nsz;
        qx = nqx; qy = nqy; qz = nqz;
    }

    // ---- block-level stat partials (deterministic) ----
    csum0 += __shfl_xor(csum0, 32);
    csum1 += __shfl_xor(csum1, 32);
    csq0  += __shfl_xor(csq0, 32);
    csq1  += __shfl_xor(csq1, 32);
    if (lane < 32) {
        red[wv][col]      = csum0;
        red[wv][32 + col] = csum1;
        red[wv][64 + col] = csq0;
        red[wv][96 + col] = csq1;
    }
    __syncthreads();
    if (tid < 128) {
        const float v = red[0][tid] + red[1][tid] + red[2][tid] + red[3][tid];
        partials[blockIdx.x * 128 + tid] = v;
    }
}

// One block per channel: deterministic tree reduction over GRIDM partials.
__global__ void gc_finalize(const float* __restrict__ partials,
                            const float* __restrict__ gamma,
                            const float* __restrict__ beta,
                            float* __restrict__ sb)
{
    __shared__ double rs[256], rq[256];
    const int o = blockIdx.x;     // channel
    const int t = threadIdx.x;    // 256
    double s = 0.0, qq = 0.0;
    for (int b = t; b < GRIDM; b += 256) {
        s  += (double)partials[b * 128 + o];
        qq += (double)partials[b * 128 + 64 + o];
    }
    rs[t] = s; rq[t] = qq;
    __syncthreads();
    for (int w2 = 128; w2 > 0; w2 >>= 1) {
        if (t < w2) { rs[t] += rs[t + w2]; rq[t] += rq[t + w2]; }
        __syncthreads();
    }
    if (t == 0) {
        const double n = (double)NQ * (double)KK;
        const double mean = rs[0] / n;
        const double var  = rq[0] / n - mean * mean;
        const float sc = gamma[o] * (float)(1.0 / sqrt(var + 1e-5));
        const float bi = beta[o] - (float)mean * sc;
        sb[o]      = sc;
        sb[64 + o] = bi;
    }
}

// out = leaky(scale * z + bias), in place on d_out (float4-wide).
__global__ void gc_bnact(float4* __restrict__ out,
                         const float4* __restrict__ zmin,
                         const float* __restrict__ sb,
                         int has_min)
{
    const int i  = blockIdx.x * 256 + threadIdx.x;   // < NQ*CO/4
    const int ob = (i & 15) * 4;
    const float4 s4 = *(const float4*)(sb + ob);
    const float4 b4 = *(const float4*)(sb + 64 + ob);
    float4 z4 = out[i];
    if (has_min) {
        const float4 n4 = zmin[i];
        if (s4.x < 0.f) z4.x = n4.x;
        if (s4.y < 0.f) z4.y = n4.y;
        if (s4.z < 0.f) z4.z = n4.z;
        if (s4.w < 0.f) z4.w = n4.w;
    }
    float4 v;
    v.x = s4.x * z4.x + b4.x;
    v.y = s4.y * z4.y + b4.y;
    v.z = s4.z * z4.z + b4.z;
    v.w = s4.w * z4.w + b4.w;
    v.x = (v.x >= 0.f) ? v.x : 0.1f * v.x;
    v.y = (v.y >= 0.f) ? v.y : 0.1f * v.y;
    v.z = (v.z >= 0.f) ? v.z : 0.1f * v.z;
    v.w = (v.w >= 0.f) ? v.w : 0.1f * v.w;
    out[i] = v;
}

extern "C" void kernel_launch(void* const* d_in, const int* in_sizes, int n_in,
                              void* d_out, int out_size, void* d_ws, size_t ws_size,
                              hipStream_t stream) {
    const float* q_points = (const float*)d_in[0];
    const float* s_points = (const float*)d_in[1];
    const float* feat     = (const float*)d_in[2];
    const float* conv_w   = (const float*)d_in[3];
    const float* gamma    = (const float*)d_in[4];
    const float* beta     = (const float*)d_in[5];
    const int*   inds     = (const int*)d_in[6];

    float* ws   = (float*)d_ws;
    float* sb   = ws;                              // 128 floats
    float* par  = ws + 128;                        // GRIDM*128 floats
    float* ftab = par + GRIDM * 128;               // (NS+1)*64 bf16 = 1600032 floats
    float* zmn  = ftab + 1600032;                  // NQ*CO floats (optional)

    const size_t need_tab = (size_t)(128 + GRIDM * 128 + 1600032) * 4;
    const size_t need_min = need_tab + (size_t)NQ * CO * 4;
    const bool has_tab = ws_size >= need_tab;
    const bool has_min = ws_size >= need_min;

    float* zmax = (float*)d_out;
    bf16x8* fbf = (bf16x8*)ftab;

    if (has_tab) {
        gc_tobf16<<<((NS + 1) * CF / 8 + 255) / 256, 256, 0, stream>>>(feat, fbf);
        if (has_min) {
            gc_mfma<true, true><<<GRIDM, 256, 0, stream>>>(
                q_points, s_points, feat, fbf, conv_w, inds, zmax, zmn, par);
        } else {
            gc_mfma<true, false><<<GRIDM, 256, 0, stream>>>(
                q_points, s_points, feat, fbf, conv_w, inds, zmax, nullptr, par);
        }
    } else {
        gc_mfma<false, false><<<GRIDM, 256, 0, stream>>>(
            q_points, s_points, feat, nullptr, conv_w, inds, zmax, nullptr, par);
    }
    gc_finalize<<<64, 256, 0, stream>>>(par, gamma, beta, sb);
    gc_bnact<<<(NQ * CO / 4 + 255) / 256, 256, 0, stream>>>(
        (float4*)d_out, (const float4*)zmn, sb, has_min && has_tab ? 1 : 0);
}

// Round 8
// 72.160 us; speedup vs baseline: 1.8953x; 1.8953x over previous
//
#include <hip/hip_runtime.h>
#include <hip/hip_bf16.h>
#include <math.h>

#define NQ 50000
#define NS 50000
#define KK 32
#define CF 64      // feat channels
#define CW 67      // conv input channels (3 + 64)
#define CO 64      // output channels
#define WAVES 4
#define GRIDM 768             // 3 blocks/CU at <=170 VGPR
#define GS2 (GRIDM * WAVES)   // 3072 queries per grid-stride step

typedef __attribute__((ext_vector_type(8))) short bf16x8;
typedef __attribute__((ext_vector_type(16))) float f32x16;

__device__ inline short f2b(float x) {
    union { __hip_bfloat16 b; short s; } u;
    u.b = __float2bfloat16(x);   // RNE
    return u.s;
}

__device__ inline bf16x8 pack2(const float4 a, const float4 b) {
    bf16x8 r;
    r[0] = f2b(a.x); r[1] = f2b(a.y); r[2] = f2b(a.z); r[3] = f2b(a.w);
    r[4] = f2b(b.x); r[5] = f2b(b.y); r[6] = f2b(b.z); r[7] = f2b(b.w);
    return r;
}

__device__ inline bf16x8 zero8() {
    bf16x8 r;
#pragma unroll
    for (int j = 0; j < 8; ++j) r[j] = 0;
    return r;
}

// feat f32 [NS][64] -> bf16 table [NS+1][64] (row NS = zeros).
__global__ __launch_bounds__(256) void gc_tobf16(const float* __restrict__ feat,
                                                 bf16x8* __restrict__ fbf)
{
    const int i = blockIdx.x * 256 + threadIdx.x;     // short8 index
    if (i >= (NS + 1) * CF / 8) return;
    bf16x8 r;
    if (i < NS * CF / 8) {
        const float4* fp = (const float4*)feat + (size_t)i * 2;
        r = pack2(fp[0], fp[1]);
    } else {
        r = zero8();
    }
    fbf[i] = r;
}

// Load one pipeline stage: 4 bf16x8 A-fragments + support coords.
template <bool TAB>
__device__ inline void load_stage(const bf16x8* __restrict__ fbf,
                                  const float* __restrict__ feat,
                                  const float* __restrict__ sp,
                                  int ii, int half,
                                  bf16x8& F0, bf16x8& F1, bf16x8& F2, bf16x8& F3,
                                  float& sx, float& sy, float& sz)
{
    if (TAB) {
        const bf16x8* frow = fbf + (size_t)ii * 8;   // row NS is zeros
        F0 = frow[half]; F1 = frow[2 + half]; F2 = frow[4 + half]; F3 = frow[6 + half];
    } else {
        const bool v = (ii < NS);
        const int iic = v ? ii : 0;
        const float4* fp = (const float4*)(feat + (size_t)iic * CF);
        F0 = pack2(fp[half * 2], fp[half * 2 + 1]);
        F1 = pack2(fp[4 + half * 2], fp[4 + half * 2 + 1]);
        F2 = pack2(fp[8 + half * 2], fp[8 + half * 2 + 1]);
        F3 = pack2(fp[12 + half * 2], fp[12 + half * 2 + 1]);
        if (!v) { F0 = zero8(); F1 = zero8(); F2 = zero8(); F3 = zero8(); }
    }
    const int iis = (ii < NS) ? ii : 0;
    sx = sp[iis * 3 + 0]; sy = sp[iis * 3 + 1]; sz = sp[iis * 3 + 2];
}

// One wave = one query per iteration. M=32 neighbors, N=64 (2 tiles of 32),
// K=80 (k0..63 = feat via bf16 table, k64..66 = rel coords).
// 2-deep software pipeline: data for q+GS and q+2GS in flight; idx 3 ahead.
template <bool TAB, bool MIN>
__global__ __launch_bounds__(256, 3) void gc_mfma(
    const float* __restrict__ qp,
    const float* __restrict__ sp,
    const float* __restrict__ feat,
    const bf16x8* __restrict__ fbf,   // [NS+1][8] short8 rows
    const float* __restrict__ w,      // [64][67]
    const int*   __restrict__ inds,
    float* __restrict__ zmax,         // d_out [NQ][64]
    float* __restrict__ zmin,         // ws (optional)
    float* __restrict__ partials)     // [GRIDM][128]
{
    __shared__ float red[WAVES][128];

    const int tid  = threadIdx.x;
    const int lane = tid & 63;
    const int wv   = tid >> 6;
    const int col  = lane & 31;
    const int half = lane >> 5;

    // ---- B fragments (weights), register-resident, built once ----
    bf16x8 bfrag[5][2];
#pragma unroll
    for (int c = 0; c < 5; ++c) {
#pragma unroll
        for (int t = 0; t < 2; ++t) {
            const int o = t * 32 + col;
            bf16x8 r;
#pragma unroll
            for (int j = 0; j < 8; ++j) {
                const int k = c * 16 + half * 8 + j;
                float v = 0.f;
                if (k < 64)      v = w[o * CW + 3 + k];
                else if (k < 67) v = w[o * CW + (k - 64)];
                r[j] = f2b(v);
            }
            bfrag[c][t] = r;
        }
    }

    float csum0 = 0.f, csum1 = 0.f, csq0 = 0.f, csq1 = 0.f;

    // ---- pipeline prologue ----
    int q = blockIdx.x * WAVES + wv;          // < GS2 <= NQ
    int i0 = inds[q * KK + col];
    bf16x8 A0, A1, A2, A3; float a_sx, a_sy, a_sz;
    load_stage<TAB>(fbf, feat, sp, i0, half, A0, A1, A2, A3, a_sx, a_sy, a_sz);

    int q1 = q + GS2;
    int i1 = 0;
    bf16x8 B0, B1, B2, B3; float b_sx = 0.f, b_sy = 0.f, b_sz = 0.f;
    if (q1 < NQ) {
        i1 = inds[q1 * KK + col];
        load_stage<TAB>(fbf, feat, sp, i1, half, B0, B1, B2, B3, b_sx, b_sy, b_sz);
    }
    int q2 = q1 + GS2;
    int i2 = (q2 < NQ) ? inds[q2 * KK + col] : 0;

    while (true) {
        // ---- coord fragment (k=64..66) for current query ----
        const bool vc = (i0 < NS);
        const float qx = qp[q * 3 + 0];   // wave-uniform -> s_load
        const float qy = qp[q * 3 + 1];
        const float qz = qp[q * 3 + 2];
        bf16x8 a4 = zero8();
        if (half == 0) {
            a4[0] = f2b(vc ? a_sx - qx : 0.f);
            a4[1] = f2b(vc ? a_sy - qy : 0.f);
            a4[2] = f2b(vc ? a_sz - qz : 0.f);
        }

        // ---- issue stage q+2GS loads (cover MFMA+epilogue of 2 iterations) ----
        const bool have2 = (q2 < NQ);   // wave-uniform
        bf16x8 C0, C1, C2, C3; float c_sx = 0.f, c_sy = 0.f, c_sz = 0.f;
        int i3 = 0;
        if (have2) {
            load_stage<TAB>(fbf, feat, sp, i2, half, C0, C1, C2, C3, c_sx, c_sy, c_sz);
            const int q3 = q2 + GS2;
            if (q3 < NQ) i3 = inds[q3 * KK + col];
        }

        // ---- MFMA: C[32 rows=neighbors][64 cols=channels] ----
        f32x16 acc0, acc1;
#pragma unroll
        for (int r = 0; r < 16; ++r) { acc0[r] = 0.f; acc1[r] = 0.f; }
        acc0 = __builtin_amdgcn_mfma_f32_32x32x16_bf16(A0, bfrag[0][0], acc0, 0, 0, 0);
        acc1 = __builtin_amdgcn_mfma_f32_32x32x16_bf16(A0, bfrag[0][1], acc1, 0, 0, 0);
        acc0 = __builtin_amdgcn_mfma_f32_32x32x16_bf16(A1, bfrag[1][0], acc0, 0, 0, 0);
        acc1 = __builtin_amdgcn_mfma_f32_32x32x16_bf16(A1, bfrag[1][1], acc1, 0, 0, 0);
        acc0 = __builtin_amdgcn_mfma_f32_32x32x16_bf16(A2, bfrag[2][0], acc0, 0, 0, 0);
        acc1 = __builtin_amdgcn_mfma_f32_32x32x16_bf16(A2, bfrag[2][1], acc1, 0, 0, 0);
        acc0 = __builtin_amdgcn_mfma_f32_32x32x16_bf16(A3, bfrag[3][0], acc0, 0, 0, 0);
        acc1 = __builtin_amdgcn_mfma_f32_32x32x16_bf16(A3, bfrag[3][1], acc1, 0, 0, 0);
        acc0 = __builtin_amdgcn_mfma_f32_32x32x16_bf16(a4, bfrag[4][0], acc0, 0, 0, 0);
        acc1 = __builtin_amdgcn_mfma_f32_32x32x16_bf16(a4, bfrag[4][1], acc1, 0, 0, 0);

        // ---- epilogue: per-col max over 32 rows + sum/sumsq ----
        float m0 = acc0[0], m1 = acc1[0];
        float n0 = acc0[0], n1 = acc1[0];
        float s0 = 0.f, s1 = 0.f, qq0 = 0.f, qq1 = 0.f;
#pragma unroll
        for (int r = 0; r < 16; ++r) {
            const float z0 = acc0[r], z1 = acc1[r];
            m0 = fmaxf(m0, z0); m1 = fmaxf(m1, z1);
            if (MIN) { n0 = fminf(n0, z0); n1 = fminf(n1, z1); }
            s0 += z0; s1 += z1;
            qq0 = fmaf(z0, z0, qq0); qq1 = fmaf(z1, z1, qq1);
        }
        csum0 += s0; csum1 += s1; csq0 += qq0; csq1 += qq1;

        m0 = fmaxf(m0, __shfl_xor(m0, 32));
        m1 = fmaxf(m1, __shfl_xor(m1, 32));
        zmax[q * CO + half * 32 + col] = half ? m1 : m0;
        if (MIN) {
            n0 = fminf(n0, __shfl_xor(n0, 32));
            n1 = fminf(n1, __shfl_xor(n1, 32));
            zmin[q * CO + half * 32 + col] = half ? n1 : n0;
        }

        if (q1 >= NQ) break;
        q = q1; q1 = q2; q2 += GS2;
        i0 = i1; i1 = i2; i2 = i3;
        A0 = B0; A1 = B1; A2 = B2; A3 = B3;
        a_sx = b_sx; a_sy = b_sy; a_sz = b_sz;
        B0 = C0; B1 = C1; B2 = C2; B3 = C3;
        b_sx = c_sx; b_sy = c_sy; b_sz = c_sz;
    }

    // ---- block-level stat partials (deterministic) ----
    csum0 += __shfl_xor(csum0, 32);
    csum1 += __shfl_xor(csum1, 32);
    csq0  += __shfl_xor(csq0, 32);
    csq1  += __shfl_xor(csq1, 32);
    if (lane < 32) {
        red[wv][col]      = csum0;
        red[wv][32 + col] = csum1;
        red[wv][64 + col] = csq0;
        red[wv][96 + col] = csq1;
    }
    __syncthreads();
    if (tid < 128) {
        const float v = red[0][tid] + red[1][tid] + red[2][tid] + red[3][tid];
        partials[blockIdx.x * 128 + tid] = v;
    }
}

// One block per channel: deterministic tree reduction over GRIDM partials.
__global__ void gc_finalize(const float* __restrict__ partials,
                            const float* __restrict__ gamma,
                            const float* __restrict__ beta,
                            float* __restrict__ sb)
{
    __shared__ double rs[256], rq[256];
    const int o = blockIdx.x;     // channel
    const int t = threadIdx.x;    // 256
    double s = 0.0, qq = 0.0;
    for (int b = t; b < GRIDM; b += 256) {
        s  += (double)partials[b * 128 + o];
        qq += (double)partials[b * 128 + 64 + o];
    }
    rs[t] = s; rq[t] = qq;
    __syncthreads();
    for (int w2 = 128; w2 > 0; w2 >>= 1) {
        if (t < w2) { rs[t] += rs[t + w2]; rq[t] += rq[t + w2]; }
        __syncthreads();
    }
    if (t == 0) {
        const double n = (double)NQ * (double)KK;
        const double mean = rs[0] / n;
        const double var  = rq[0] / n - mean * mean;
        const float sc = gamma[o] * (float)(1.0 / sqrt(var + 1e-5));
        const float bi = beta[o] - (float)mean * sc;
        sb[o]      = sc;
        sb[64 + o] = bi;
    }
}

// out = leaky(scale * z + bias), in place on d_out (float4-wide).
// zmin only read if some scale is negative (never in practice: gamma=1).
__global__ void gc_bnact(float4* __restrict__ out,
                         const float4* __restrict__ zmin,
                         const float* __restrict__ sb,
                         int has_min)
{
    const int i  = blockIdx.x * 256 + threadIdx.x;   // < NQ*CO/4
    const int ob = (i & 15) * 4;
    const float4 s4 = *(const float4*)(sb + ob);
    const float4 b4 = *(const float4*)(sb + 64 + ob);
    float4 z4 = out[i];
    if (has_min && (s4.x < 0.f || s4.y < 0.f || s4.z < 0.f || s4.w < 0.f)) {
        const float4 n4 = zmin[i];
        if (s4.x < 0.f) z4.x = n4.x;
        if (s4.y < 0.f) z4.y = n4.y;
        if (s4.z < 0.f) z4.z = n4.z;
        if (s4.w < 0.f) z4.w = n4.w;
    }
    float4 v;
    v.x = s4.x * z4.x + b4.x;
    v.y = s4.y * z4.y + b4.y;
    v.z = s4.z * z4.z + b4.z;
    v.w = s4.w * z4.w + b4.w;
    v.x = (v.x >= 0.f) ? v.x : 0.1f * v.x;
    v.y = (v.y >= 0.f) ? v.y : 0.1f * v.y;
    v.z = (v.z >= 0.f) ? v.z : 0.1f * v.z;
    v.w = (v.w >= 0.f) ? v.w : 0.1f * v.w;
    out[i] = v;
}

extern "C" void kernel_launch(void* const* d_in, const int* in_sizes, int n_in,
                              void* d_out, int out_size, void* d_ws, size_t ws_size,
                              hipStream_t stream) {
    const float* q_points = (const float*)d_in[0];
    const float* s_points = (const float*)d_in[1];
    const float* feat     = (const float*)d_in[2];
    const float* conv_w   = (const float*)d_in[3];
    const float* gamma    = (const float*)d_in[4];
    const float* beta     = (const float*)d_in[5];
    const int*   inds     = (const int*)d_in[6];

    float* ws   = (float*)d_ws;
    float* sb   = ws;                              // 128 floats
    float* par  = ws + 128;                        // GRIDM*128 floats
    float* ftab = par + GRIDM * 128;               // (NS+1)*64 bf16 = 1600032 floats
    float* zmn  = ftab + 1600032;                  // NQ*CO floats (optional)

    const size_t need_tab = (size_t)(128 + GRIDM * 128 + 1600032) * 4;
    const size_t need_min = need_tab + (size_t)NQ * CO * 4;
    const bool has_tab = ws_size >= need_tab;
    const bool has_min = ws_size >= need_min;

    float* zmax = (float*)d_out;
    bf16x8* fbf = (bf16x8*)ftab;

    if (has_tab) {
        gc_tobf16<<<((NS + 1) * CF / 8 + 255) / 256, 256, 0, stream>>>(feat, fbf);
        if (has_min) {
            gc_mfma<true, true><<<GRIDM, 256, 0, stream>>>(
                q_points, s_points, feat, fbf, conv_w, inds, zmax, zmn, par);
        } else {
            gc_mfma<true, false><<<GRIDM, 256, 0, stream>>>(
                q_points, s_points, feat, fbf, conv_w, inds, zmax, nullptr, par);
        }
    } else {
        gc_mfma<false, false><<<GRIDM, 256, 0, stream>>>(
            q_points, s_points, feat, nullptr, conv_w, inds, zmax, nullptr, par);
    }
    gc_finalize<<<64, 256, 0, stream>>>(par, gamma, beta, sb);
    gc_bnact<<<(NQ * CO / 4 + 255) / 256, 256, 0, stream>>>(
        (float4*)d_out, (const float4*)zmn, sb, has_min && has_tab ? 1 : 0);
}